// Round 2
// baseline (186.012 us; speedup 1.0000x reference)
//
#include <hip/hip_runtime.h>
#include <hip/hip_bf16.h>
#include <stdint.h>

#define N_PTS   4096
#define M_CODES 4096
#define ZDIM    1024
#define BM 128
#define BN 128
#define BK 64
#define NBLOCKS ((N_PTS / BM) * (M_CODES / BN))

typedef __attribute__((ext_vector_type(8))) short bf16x8;
typedef __attribute__((ext_vector_type(4))) float f32x4;

__device__ __forceinline__ unsigned short f2bf(float f) {
    __hip_bfloat16 h = __float2bfloat16(f);
    return *reinterpret_cast<unsigned short*>(&h);
}

// order-preserving float -> uint map (monotone): enables atomicMin on uint
__device__ __forceinline__ unsigned enc_f32(float f) {
    unsigned u = __float_as_uint(f);
    return (u & 0x80000000u) ? ~u : (u | 0x80000000u);
}
__device__ __forceinline__ float dec_f32(unsigned e) {
    unsigned u = (e & 0x80000000u) ? (e ^ 0x80000000u) : ~e;
    return __uint_as_float(u);
}

// ---------------------------------------------------------------------------
// prep: fp32 -> bf16 cast of z and e, row sum-of-squares, min/counter init.
// One wave per row: grid = 2048 blocks x 256 threads (4 rows/block).
// No LDS, no __syncthreads.
// ---------------------------------------------------------------------------
__global__ __launch_bounds__(256) void prep_kernel(
    const float* __restrict__ z, const float* __restrict__ e,
    unsigned short* __restrict__ zb, unsigned short* __restrict__ eb,
    float* __restrict__ zsq, float* __restrict__ esq,
    unsigned* __restrict__ min_enc, unsigned* __restrict__ done_counter) {
    const int t = threadIdx.x;
    const int b = blockIdx.x;
    if (b < 16) min_enc[b * 256 + t] = 0xFFFFFFFFu;  // encodes "+huge"
    if (b == 16 && t == 0) *done_counter = 0u;

    const int w = t >> 6, lane = t & 63;
    const int row = b * 4 + w;  // 0..8191
    const float* src;
    unsigned short* dst;
    float* sqp;
    if (row < N_PTS) {
        src = z + (size_t)row * ZDIM; dst = zb + (size_t)row * ZDIM; sqp = zsq + row;
    } else {
        const int r = row - N_PTS;
        src = e + (size_t)r * ZDIM; dst = eb + (size_t)r * ZDIM; sqp = esq + r;
    }
    const float4* s4 = reinterpret_cast<const float4*>(src);
    ushort4* d4 = reinterpret_cast<ushort4*>(dst);
    float s = 0.f;
    #pragma unroll
    for (int i = 0; i < 4; i++) {
        float4 v = s4[i * 64 + lane];
        ushort4 o;
        o.x = f2bf(v.x); o.y = f2bf(v.y); o.z = f2bf(v.z); o.w = f2bf(v.w);
        d4[i * 64 + lane] = o;
        s += v.x * v.x + v.y * v.y + v.z * v.z + v.w * v.w;
    }
    #pragma unroll
    for (int off = 1; off < 64; off <<= 1) s += __shfl_xor(s, off, 64);
    if (lane == 0) *sqp = s;
}

// ---------------------------------------------------------------------------
// gemm_min: 128x128x64-stage bf16 MFMA, XOR-8 LDS swizzle (conflict-free),
// fused column-min epilogue + fused finalize in the last-done block.
// grid = (32, 32), 256 threads = 4 waves (2x2 of 64x64).
//
// LDS layout: [128 rows][128 B]; logical 16B chunk c of row r stored at
// physical chunk c^(r&7). Swizzle applied in the *global* source address of
// global_load_lds so the LDS destination stays lane-contiguous.
// ---------------------------------------------------------------------------
__global__ __launch_bounds__(256) void gemm_min_kernel(
    const unsigned short* __restrict__ zb, const unsigned short* __restrict__ eb,
    const float* __restrict__ zsq, const float* __restrict__ esq,
    unsigned* __restrict__ min_enc, unsigned* __restrict__ done_counter,
    float* __restrict__ out) {
    __shared__ __align__(16) unsigned short As[BM * BK];  // 16 KB
    __shared__ __align__(16) unsigned short Bs[BN * BK];  // 16 KB
    __shared__ float zsq_s[BM];
    __shared__ float colmin[2][BN];
    __shared__ float red[4];
    __shared__ int last_flag;

    const int t = threadIdx.x;
    const int bx = blockIdx.x;  // code (col) block
    const int by = blockIdx.y;  // point (row) block
    const int lane = t & 63;
    const int w = t >> 6;
    const int wm = w >> 1, wn = w & 1;
    const int lrow = lane & 15;
    const int q = lane >> 4;

    if (t < BM) zsq_s[t] = zsq[by * BM + t];

    f32x4 acc[4][4];
    #pragma unroll
    for (int i = 0; i < 4; i++)
        #pragma unroll
        for (int j = 0; j < 4; j++) acc[i][j] = (f32x4){0.f, 0.f, 0.f, 0.f};

    // staging geometry: per instr j (j=0..3), thread t covers LDS bytes
    // j*4096 + t*16 -> physical row j*32 + (t>>3), physical chunk t&7.
    // Loaded logical chunk = (t&7) ^ ((t>>3)&7)  [XOR-8 swizzle].
    const int rloc = t >> 3;                      // 0..31
    const int sw = (t & 7) ^ (rloc & 7);          // logical chunk to fetch
    const int ldsw = (t >> 6) * 512;              // wave-uniform base (elements)
    const size_t a_base = (size_t)(by * BM) * ZDIM;
    const size_t b_base = (size_t)(bx * BN) * ZDIM;
    const int swz = lrow & 7;                     // reader-side swizzle mask

    for (int k0 = 0; k0 < ZDIM; k0 += BK) {
        #pragma unroll
        for (int j = 0; j < 4; j++) {
            const unsigned short* ga =
                zb + a_base + (size_t)(j * 32 + rloc) * ZDIM + k0 + sw * 8;
            const unsigned short* gb =
                eb + b_base + (size_t)(j * 32 + rloc) * ZDIM + k0 + sw * 8;
            __builtin_amdgcn_global_load_lds(
                (const __attribute__((address_space(1))) void*)ga,
                (__attribute__((address_space(3))) void*)(As + j * 2048 + ldsw), 16, 0, 0);
            __builtin_amdgcn_global_load_lds(
                (const __attribute__((address_space(1))) void*)gb,
                (__attribute__((address_space(3))) void*)(Bs + j * 2048 + ldsw), 16, 0, 0);
        }
        __syncthreads();

        #pragma unroll
        for (int s = 0; s < 2; s++) {
            bf16x8 a[4], b[4];
            #pragma unroll
            for (int am = 0; am < 4; am++) {
                const int R = wm * 64 + am * 16 + lrow;
                a[am] = *(const bf16x8*)(As + R * BK + (((q + 4 * s) ^ swz) * 8));
            }
            #pragma unroll
            for (int an = 0; an < 4; an++) {
                const int R = wn * 64 + an * 16 + lrow;
                b[an] = *(const bf16x8*)(Bs + R * BK + (((q + 4 * s) ^ swz) * 8));
            }
            #pragma unroll
            for (int am = 0; am < 4; am++)
                #pragma unroll
                for (int an = 0; an < 4; an++)
                    acc[am][an] = __builtin_amdgcn_mfma_f32_16x16x32_bf16(
                        a[am], b[an], acc[am][an], 0, 0, 0);
        }
        __syncthreads();
    }

    // Epilogue: per-lane min over (am, reg), cross-lane over q, LDS-combine
    // the two wm waves, one atomicMin per column per block.
    // C/D layout: row = q*4+r, col = lrow (m89-verified).
    #pragma unroll
    for (int an = 0; an < 4; an++) {
        float v = 3.4e38f;
        #pragma unroll
        for (int am = 0; am < 4; am++) {
            const int rbase = wm * 64 + am * 16 + q * 4;
            f32x4 c = acc[am][an];
            v = fminf(v, zsq_s[rbase + 0] - 2.f * c[0]);
            v = fminf(v, zsq_s[rbase + 1] - 2.f * c[1]);
            v = fminf(v, zsq_s[rbase + 2] - 2.f * c[2]);
            v = fminf(v, zsq_s[rbase + 3] - 2.f * c[3]);
        }
        v = fminf(v, __shfl_xor(v, 16, 64));
        v = fminf(v, __shfl_xor(v, 32, 64));
        if (q == 0) colmin[wm][wn * 64 + an * 16 + lrow] = v;
    }
    __syncthreads();
    if (t < BN) {
        const float m = fminf(colmin[0][t], colmin[1][t]);
        atomicMin(&min_enc[bx * BN + t], enc_f32(m));
    }

    // Fused finalize: last block to finish reduces min_enc -> mean -> out.
    __threadfence();
    if (t == 0) {
        unsigned old = atomicAdd(done_counter, 1u);
        last_flag = (old == (unsigned)(NBLOCKS - 1));
    }
    __syncthreads();
    if (last_flag) {
        __threadfence();  // acquire side
        float s = 0.f;
        #pragma unroll
        for (int i = 0; i < M_CODES / 256; i++) {
            const int j = i * 256 + t;
            unsigned enc = __hip_atomic_load(&min_enc[j], __ATOMIC_RELAXED,
                                             __HIP_MEMORY_SCOPE_AGENT);
            s += dec_f32(enc) + esq[j];
        }
        #pragma unroll
        for (int off = 1; off < 64; off <<= 1) s += __shfl_xor(s, off, 64);
        if ((t & 63) == 0) red[t >> 6] = s;
        __syncthreads();
        if (t == 0)
            out[0] = (red[0] + red[1] + red[2] + red[3]) * (1.f / M_CODES);
    }
}

extern "C" void kernel_launch(void* const* d_in, const int* in_sizes, int n_in,
                              void* d_out, int out_size, void* d_ws, size_t ws_size,
                              hipStream_t stream) {
    (void)in_sizes; (void)n_in; (void)out_size; (void)ws_size;
    const float* z = (const float*)d_in[0];
    const float* e = (const float*)d_in[1];
    char* ws = (char*)d_ws;
    unsigned short* zb = (unsigned short*)ws;                           // 8 MB
    unsigned short* eb = (unsigned short*)(ws + ((size_t)8 << 20));     // 8 MB
    float* zsq = (float*)(ws + ((size_t)16 << 20));                     // 16 KB
    float* esq = (float*)(ws + ((size_t)16 << 20) + 4096 * 4);          // 16 KB
    unsigned* min_enc = (unsigned*)(ws + ((size_t)16 << 20) + 2 * 4096 * 4);  // 16 KB
    unsigned* done_counter = (unsigned*)(ws + ((size_t)16 << 20) + 3 * 4096 * 4);

    prep_kernel<<<dim3(2048), dim3(256), 0, stream>>>(
        z, e, zb, eb, zsq, esq, min_enc, done_counter);
    gemm_min_kernel<<<dim3(M_CODES / BN, N_PTS / BM), dim3(256), 0, stream>>>(
        zb, eb, zsq, esq, min_enc, done_counter, (float*)d_out);
}